// Round 16
// baseline (1077.268 us; speedup 1.0000x reference)
//
#include <hip/hip_runtime.h>
#include <math.h>

#define T_STEPS 4096
#define B_N     512
#define CHUNK   4
#define NFULL   1023   // full chunks 0..1022 (4 steps): t = 1..4092
// tail chunk 1023: 3 steps, t = 4093..4095; pprm buf 1023%5==3, outs buf 1023%3==0

typedef float f2 __attribute__((ext_vector_type(2)));

// ---- packed-f32 VOP3P helpers (verified r10-r15, absmax 0.0) ----
__device__ __forceinline__ f2 pk_fma(f2 a, f2 b, f2 c){ f2 d; asm("v_pk_fma_f32 %0, %1, %2, %3" : "=v"(d) : "v"(a), "v"(b), "v"(c)); return d; }
__device__ __forceinline__ f2 pk_mul(f2 a, f2 b){ f2 d; asm("v_pk_mul_f32 %0, %1, %2" : "=v"(d) : "v"(a), "v"(b)); return d; }
__device__ __forceinline__ f2 pk_add(f2 a, f2 b){ f2 d; asm("v_pk_add_f32 %0, %1, %2" : "=v"(d) : "v"(a), "v"(b)); return d; }
__device__ __forceinline__ f2 pk_sub(f2 a, f2 b){ f2 d; asm("v_pk_add_f32 %0, %1, %2 neg_lo:[0,1] neg_hi:[0,1]" : "=v"(d) : "v"(a), "v"(b)); return d; }
__device__ __forceinline__ f2 pk_dd(f2 dP){ f2 d; asm("v_pk_add_f32 %0, %1, %1 op_sel:[0,1] op_sel_hi:[0,1] neg_lo:[0,1] neg_hi:[0,0]" : "=v"(d) : "v"(dP)); return d; }
// aP=(x,y) -> (y-x, x+y)  : (dqd, ssum) in one op
__device__ __forceinline__ f2 pk_dq(f2 aP){ f2 d; asm("v_pk_add_f32 %0, %1, %1 op_sel:[0,1] op_sel_hi:[0,1] neg_lo:[1,0] neg_hi:[0,0]" : "=v"(d) : "v"(aP)); return d; }
__device__ __forceinline__ f2 pk_vq(f2 a, f2 b){ f2 d; asm("v_pk_add_f32 %0, %1, %2 op_sel:[0,1] op_sel_hi:[1,0]" : "=v"(d) : "v"(a), "v"(b)); return d; }
__device__ __forceinline__ f2 pk_t01a(f2 pq, f2 qA){ f2 d; asm("v_pk_mul_f32 %0, %1, %2 op_sel:[0,1] op_sel_hi:[0,0]" : "=v"(d) : "v"(pq), "v"(qA)); return d; }
__device__ __forceinline__ f2 pk_t01b(f2 pq, f2 qB, f2 acc){ asm("v_pk_fma_f32 %0, %1, %2, %0 op_sel:[1,0,0] op_sel_hi:[1,1,1] neg_hi:[0,1,0]" : "+v"(acc) : "v"(pq), "v"(qB)); return acc; }
__device__ __forceinline__ f2 pk_t01c(f2 rz, f2 qB, f2 acc){ asm("v_pk_fma_f32 %0, %1, %2, %0 op_sel:[0,1,0] op_sel_hi:[0,0,1]" : "+v"(acc) : "v"(rz), "v"(qB)); return acc; }
__device__ __forceinline__ f2 pk_t23a(f2 pq, f2 qA){ f2 d; asm("v_pk_mul_f32 %0, %1, %2 op_sel:[1,0] op_sel_hi:[1,1]" : "=v"(d) : "v"(pq), "v"(qA)); return d; }
__device__ __forceinline__ f2 pk_t23b(f2 pq, f2 qB, f2 acc){ asm("v_pk_fma_f32 %0, %1, %2, %0 op_sel:[0,1,0] op_sel_hi:[0,0,1] neg_hi:[0,1,0]" : "+v"(acc) : "v"(pq), "v"(qB)); return acc; }
__device__ __forceinline__ f2 pk_t23c(f2 rz, f2 qA, f2 acc){ asm("v_pk_fma_f32 %0, %1, %2, %0 op_sel:[0,1,0] op_sel_hi:[0,0,1] neg_lo:[0,1,0]" : "+v"(acc) : "v"(rz), "v"(qA)); return acc; }
__device__ __forceinline__ f2 pk_s1p(f2 pq, f2 rz){ f2 d; asm("v_pk_mul_f32 %0, %1, %2 op_sel:[1,0] op_sel_hi:[0,0]" : "=v"(d) : "v"(pq), "v"(rz)); return d; }
__device__ __forceinline__ f2 pk_s2p(f2 pq, f2 ws){ f2 d; asm("v_pk_mul_f32 %0, %1, %2 op_sel:[1,0] op_sel_hi:[0,1]" : "=v"(d) : "v"(pq), "v"(ws)); return d; }
__device__ __forceinline__ float med3f(float x, float a, float b){ float d; asm("v_med3_f32 %0, %1, %2, %3" : "=v"(d) : "v"(x), "v"(a), "v"(b)); return d; }

// bare workgroup barrier: NO implicit vmcnt/lgkm drain (r15: +16%)
#define BAR() __builtin_amdgcn_s_barrier()

// packed param layout, 5 float4 = 80B per (t,b):
// F0={KU1,KU2,KU3,KU4} F1={A,A,mn,mx} F2={cA,cC,-cB,cD}
// F3={cdym,cdxm,cE,cq} F4={cthr,-cdx,label,0}

// ================= scalar path (fallback only) =================
struct Pk {
  float KU1, KU2, KU3, KU4, A, mn, mx, cthr;
  float cdym, cdxm, cq, cdx, cA, cB, cC, cD, cE, label, pad0, pad1;
};
__device__ __forceinline__ float sc_ref(float g, float base) {
  return (1.0f + (0.5f - g) * 0.95f) * base;
}
struct Carry {
  float xz, q0, q1, q2, q3, zd, pv, qv, rv;
  float w1, w2, w3, w4, wd1, wd2, wd3, wd4;
};
__device__ __forceinline__ Pk computePk(size_t i,
    const float* __restrict__ logits,
    const float* __restrict__ u1, const float* __restrict__ u2,
    const float* __restrict__ u3, const float* __restrict__ u4,
    const float* __restrict__ mxM, const float* __restrict__ mnM,
    const float* __restrict__ labels) {
  const float4* lg = (const float4*)logits + i * 3;
  float4 l0 = lg[0], l1 = lg[1], l2 = lg[2];
  float dxm  = sc_ref(l0.x, 0.16f);
  float dym  = sc_ref(l0.y, 0.16f);
  float IBxx = sc_ref(l0.w, 0.0123f);
  float IByy = sc_ref(l1.x, 0.0123f);
  float IBzz = sc_ref(l1.y, 0.0123f);
  float Cd   = sc_ref(l1.z, 0.1f);
  float kTh  = sc_ref(l1.w, 1.076e-05f);
  float kTo  = sc_ref(l2.x, 1.632e-07f);
  float tau2 = sc_ref(l2.y, 0.015f);
  float kp   = sc_ref(l2.z, 1.0f);
  float damp = sc_ref(l2.w, 1.0f);
  const float tau = 0.005f, tauOverMb = tau / 1.2f;
  Pk p;
  float K = kp / (tau2 * tau2);
  p.KU1 = K * u1[i];  p.KU2 = K * u2[i];  p.KU3 = K * u3[i];  p.KU4 = K * u4[i];
  p.A = -2.0f * damp * tau2;
  p.mn = mnM[i];  p.mx = mxM[i];
  p.cthr = kTh * tauOverMb;
  float tx = tau / IBxx, ty = tau / IByy, tz = tau / IBzz;
  p.cdym = kTh * dym * tx;  p.cdxm = kTh * dxm * ty;
  p.cq = kTo * tz;  p.cdx = Cd * tauOverMb;
  p.cA = (IByy - IBzz) * tx;  p.cB = 1e-04f * tx;
  p.cC = (IBzz - IBxx) * ty;  p.cD = 1e-04f * ty;
  p.cE = (IBxx - IByy) * tz;
  p.label = labels[i];  p.pad0 = 0.f; p.pad1 = 0.f;
  return p;
}
__device__ __forceinline__ void stepOne(Carry& c, const Pk& p, float& facc) {
  const float TAU = 0.005f, HTAU = 0.0025f, TAUG = 0.04905f;
  float wdd1 = fmaf(p.A, c.wd1, p.KU1) - c.w1;
  float wdd2 = fmaf(p.A, c.wd2, p.KU2) - c.w2;
  float wdd3 = fmaf(p.A, c.wd3, p.KU3) - c.w3;
  float wdd4 = fmaf(p.A, c.wd4, p.KU4) - c.w4;
  float w1c = fminf(fmaxf(c.w1, p.mn), p.mx);
  float w2c = fminf(fmaxf(c.w2, p.mn), p.mx);
  float w3c = fminf(fmaxf(c.w3, p.mn), p.mx);
  float w4c = fminf(fmaxf(c.w4, p.mn), p.mx);
  float s1 = w1c*w1c, s2 = w2c*w2c, s3 = w3c*w3c, s4 = w4c*w4c;
  float sA = s1+s3, sB = s2+s4, ssum = sA+sB;
  float dymd = (s1+s4)-(s2+s3), dxmd = (s1+s2)-(s3+s4), dqd = sB-sA;
  float Thr2 = p.cthr * ssum;
  float qq = fmaf(c.q0,c.q0,c.q3*c.q3) - fmaf(c.q1,c.q1,c.q2*c.q2);
  float zdm = c.zd * fabsf(c.zd);
  float nzd = fmaf(-p.cdx, zdm, c.zd);
  nzd = fmaf(Thr2, qq, nzd) - TAUG;
  float t0 = fmaf(c.pv,c.q1, fmaf(c.qv,c.q2,  c.rv*c.q3));
  float t1 = fmaf(c.pv,c.q0, fmaf(-c.qv,c.q3, c.rv*c.q2));
  float t2 = fmaf(c.pv,c.q3, fmaf(c.qv,c.q0, -(c.rv*c.q1)));
  float t3 = fmaf(-c.pv,c.q2, fmaf(c.qv,c.q1, c.rv*c.q0));
  float nq0 = fmaf(-HTAU,t0,c.q0), nq1 = fmaf(HTAU,t1,c.q1);
  float nq2 = fmaf(HTAU,t2,c.q2),  nq3 = fmaf(HTAU,t3,c.q3);
  float wsum = (w1c-w2c)+(w3c-w4c);
  float npv = fmaf(p.cA, c.qv*c.rv, c.pv);
  npv = fmaf(-p.cB, wsum*c.qv, npv); npv = fmaf(p.cdym, dymd, npv);
  float nqv = fmaf(p.cC, c.pv*c.rv, c.qv);
  nqv = fmaf(p.cD, wsum*c.pv, nqv);  nqv = fmaf(p.cdxm, dxmd, nqv);
  float nrv = fmaf(p.cE, c.pv*c.qv, c.rv);
  nrv = fmaf(p.cq, dqd, nrv);
  float nxz = fmaf(TAU, nzd, c.xz);
  float d = nxz - c.xz;
  float xznew = (fabsf(d) <= 400.0f) ? nxz : c.xz;
  float e = xznew - p.label;
  facc = fmaf(e, e, facc);
  c.w1 = fmaf(TAU,c.wd1,w1c); c.w2 = fmaf(TAU,c.wd2,w2c);
  c.w3 = fmaf(TAU,c.wd3,w3c); c.w4 = fmaf(TAU,c.wd4,w4c);
  c.wd1 = fmaf(TAU,wdd1,c.wd1); c.wd2 = fmaf(TAU,wdd2,c.wd2);
  c.wd3 = fmaf(TAU,wdd3,c.wd3); c.wd4 = fmaf(TAU,wdd4,c.wd4);
  c.q0=nq0; c.q1=nq1; c.q2=nq2; c.q3=nq3;
  c.pv=npv; c.qv=nqv; c.rv=nrv; c.zd=nzd; c.xz=xznew;
}

__device__ __forceinline__ void gload_lds16(const void* g, void* l) {
  __builtin_amdgcn_global_load_lds(
      (const __attribute__((address_space(1))) void*)g,
      (__attribute__((address_space(3))) void*)l, 16, 0, 0);
}

// ---- kernel 2: finalize hover (8192 partials) ----
__global__ void k_hover(const float* __restrict__ partial, float* __restrict__ hover) {
  __shared__ float sm[1024];
  float a = 0.f;
  #pragma unroll
  for (int k = 0; k < 8; ++k) a += partial[threadIdx.x + k * 1024];
  sm[threadIdx.x] = a;
  __syncthreads();
  for (int s = 512; s; s >>= 1) {
    if (threadIdx.x < s) sm[threadIdx.x] += sm[threadIdx.x + s];
    __syncthreads();
  }
  if (threadIdx.x == 0) {
    float mean = sm[0] * (1.0f / 2097152.0f);
    float h = 1.2f * 9.81f / (4.0f * mean + 1e-12f);
    hover[0] = sqrtf(fmaxf(h, 1e-06f));
  }
}

// ---- kernel 3: param precompute, PACKED layout + fused kTh partial sums ----
__global__ void k_pre(const float* __restrict__ logits,
                      const float* __restrict__ u1, const float* __restrict__ u2,
                      const float* __restrict__ u3, const float* __restrict__ u4,
                      const float* __restrict__ mxM, const float* __restrict__ mnM,
                      const float* __restrict__ labels, float4* __restrict__ pack,
                      float* __restrict__ partial) {
  __shared__ float sm[256];
  size_t i = (size_t)blockIdx.x * 256 + threadIdx.x;  // 8192*256 == T*B exactly
  const float4* lg = (const float4*)logits + i * 3;
  float4 l0 = lg[0], l1 = lg[1], l2 = lg[2];
  float dxm  = sc_ref(l0.x, 0.16f);
  float dym  = sc_ref(l0.y, 0.16f);
  float IBxx = sc_ref(l0.w, 0.0123f);
  float IByy = sc_ref(l1.x, 0.0123f);
  float IBzz = sc_ref(l1.y, 0.0123f);
  float Cd   = sc_ref(l1.z, 0.1f);
  float kTh  = sc_ref(l1.w, 1.076e-05f);
  float kTo  = sc_ref(l2.x, 1.632e-07f);
  float tau2 = sc_ref(l2.y, 0.015f);
  float kp   = sc_ref(l2.z, 1.0f);
  float damp = sc_ref(l2.w, 1.0f);
  const float tau = 0.005f, tauOverMb = tau / 1.2f;
  float K = kp / (tau2 * tau2);
  float A = -2.0f * damp * tau2;
  float tx = tau / IBxx, ty = tau / IByy, tz = tau / IBzz;
  float4* dst = pack + i * 5;
  dst[0] = float4{K * u1[i], K * u2[i], K * u3[i], K * u4[i]};
  dst[1] = float4{A, A, mnM[i], mxM[i]};
  dst[2] = float4{(IByy - IBzz) * tx, (IBzz - IBxx) * ty, -1e-04f * tx, 1e-04f * ty};
  dst[3] = float4{kTh * dym * tx, kTh * dxm * ty, (IBxx - IByy) * tz, kTo * tz};
  dst[4] = float4{kTh * tauOverMb, -(Cd * tauOverMb), labels[i], 0.f};
  // fused kTh partial sum (replaces separate k_kth pass)
  sm[threadIdx.x] = kTh;
  __syncthreads();
  for (int s = 128; s; s >>= 1) {
    if (threadIdx.x < s) sm[threadIdx.x] += sm[threadIdx.x + s];
    __syncthreads();
  }
  if (threadIdx.x == 0) partial[blockIdx.x] = sm[0];
}

// ---- kernel 4: motor-split producer/consumer, bare barriers.
//      Wave A (wid==1): DMA staging + motor subsystem one chunk ahead;
//      writes O2={Thr2,mcdx,label,wsum}, O3={dqd,ssum,dymd,dxmd}.
//      Wave B (wid==0): 4 ds_reads + ~30 VALU per step (the pacer). ----
__global__ __launch_bounds__(128, 1) void k_simsp(
    const float4* __restrict__ pack,
    const float* __restrict__ labels,
    const float* __restrict__ hoverp, double* __restrict__ bsum) {
  __shared__ float4 pprm[5][CHUNK][5][64];   // 100 KB staging ring
  __shared__ float4 o2s[3][CHUNK][64];       // 12 KB
  __shared__ float4 o3s[3][CHUNK][64];       // 12 KB
  const int lane = threadIdx.x & 63;
  const int wid  = threadIdx.x >> 6;
  const int b = blockIdx.x * 32 + (lane & 31);   // 16 blocks x 32 = 512

  const char* packb = (const char*)pack + (size_t)b * 80;
  const f2 TT = {0.005f, 0.005f};
  const f2 HT = {-0.0025f, 0.0025f};
  const f2 HP = {0.0025f, 0.0025f};

  auto stage = [&](int chS, int bufS) {
    float4* dstb = &pprm[bufS][0][0][0];
    #pragma unroll
    for (int s = 0; s < CHUNK; ++s) {
      int t = 1 + chS * CHUNK + s;
      if (t > T_STEPS - 1) t = T_STEPS - 1;     // clamp (tail pad)
      const char* src = packb + (size_t)t * (B_N * 80);
      #pragma unroll
      for (int k = 0; k < 5; ++k)
        gload_lds16(src + 16 * k, (void*)(dstb + (s * 5 + k) * 64));
    }
  };

  // ---- wave A (producer): motor carry ----
  f2 w12, w34, wd12, wd34;
  auto motor4 = [&](int ch) {   // chunk ch: params pprm[ch%5], outs -> ch%3
    const int pb = ch % 5, ob = ch % 3;
    #pragma unroll
    for (int s = 0; s < CHUNK; ++s) {
      float4 F0 = pprm[pb][s][0][lane];
      float4 F1 = pprm[pb][s][1][lane];
      float4 F4 = pprm[pb][s][4][lane];
      f2 KU12 = {F0.x, F0.y}, KU34 = {F0.z, F0.w};
      f2 AA = {F1.x, F1.y};
      float mn = F1.z, mx = F1.w;
      f2 wdd12 = pk_sub(pk_fma(AA, wd12, KU12), w12);
      f2 wdd34 = pk_sub(pk_fma(AA, wd34, KU34), w34);
      f2 wc12, wc34;
      wc12.x = med3f(w12.x, mn, mx); wc12.y = med3f(w12.y, mn, mx);
      wc34.x = med3f(w34.x, mn, mx); wc34.y = med3f(w34.y, mn, mx);
      f2 s12 = pk_mul(wc12, wc12), s34 = pk_mul(wc34, wc34);
      f2 aP = pk_add(s12, s34), dP = pk_sub(s12, s34);
      f2 dq = pk_dq(aP);                    // (dqd, ssum)
      f2 dd = pk_dd(dP);                    // (dymd, dxmd)
      f2 tw = pk_add(wc12, wc34);
      float wsum = tw.x - tw.y;
      float Thr2 = F4.x * dq.y;             // cthr * ssum (same expr as stepP)
      o2s[ob][s][lane] = float4{Thr2, F4.y, F4.z, wsum};
      o3s[ob][s][lane] = float4{dq.x, dq.y, dd.x, dd.y};
      f2 nw12 = pk_fma(TT, wd12, wc12);
      f2 nw34 = pk_fma(TT, wd34, wc34);
      wd12 = pk_fma(TT, wdd12, wd12);
      wd34 = pk_fma(TT, wdd34, wd34);
      w12 = nw12; w34 = nw34;
    }
  };

  // ---- wave B (consumer) state ----
  f2 qA, qB, pq, rz;   // rz = (rv, zd)
  float xz;
  double acc = 0.0;
  struct SetB { float4 F2, F3, O2, O3; };
  auto loadB = [&](SetB& S, int pb, int ob, int s) {
    S.F2 = pprm[pb][s][2][lane];
    S.F3 = pprm[pb][s][3][lane];
    S.O2 = o2s[ob][s][lane];
    S.O3 = o3s[ob][s][lane];
  };
  auto stepB = [&](const SetB& S, float& facc) {
    const float TAU = 0.005f, TAUG = 0.04905f;
    f2 cAC = {S.F2.x, S.F2.y}, cBD = {S.F2.z, S.F2.w};
    f2 cdymxm = {S.F3.x, S.F3.y};
    float cE = S.F3.z, cq = S.F3.w;
    float Thr2 = S.O2.x, mcdx = S.O2.y, label = S.O2.z, ws = S.O2.w;
    float dqd = S.O3.x;
    f2 dd = {S.O3.z, S.O3.w};
    f2 qs1 = pk_mul(qA, qA), qs2 = pk_mul(qB, qB);
    f2 vq = pk_vq(qs1, qs2);
    float qq = vq.x - vq.y;
    float zd = rz.y;
    float zdm = zd * fabsf(zd);
    float nzd = fmaf(mcdx, zdm, zd);
    nzd = fmaf(Thr2, qq, nzd) - TAUG;
    f2 t01 = pk_t01a(pq, qA); t01 = pk_t01b(pq, qB, t01); t01 = pk_t01c(rz, qB, t01);
    f2 t23 = pk_t23a(pq, qA); t23 = pk_t23b(pq, qB, t23); t23 = pk_t23c(rz, qA, t23);
    f2 nqA = pk_fma(HT, t01, qA);
    f2 nqB = pk_fma(HP, t23, qB);
    f2 sp1 = pk_s1p(pq, rz);
    f2 ws2 = {ws, ws};
    f2 sp2 = pk_s2p(pq, ws2);
    f2 npq = pk_fma(cAC, sp1, pq);
    npq = pk_fma(cBD, sp2, npq);
    npq = pk_fma(cdymxm, dd, npq);
    float nrv = fmaf(cE, pq.x * pq.y, rz.x);
    nrv = fmaf(cq, dqd, nrv);
    float nxz = fmaf(TAU, nzd, xz);
    float dlt = nxz - xz;
    float xznew = (fabsf(dlt) <= 400.0f) ? nxz : xz;   // false for NaN/Inf
    float e = xznew - label;
    facc = fmaf(e, e, facc);
    qA = nqA; qB = nqB; pq = npq;
    rz = f2{nrv, nzd}; xz = xznew;
  };

  // ---- prologue: stage 0,1,2; certify 0; motor(0) -> outs[0] ----
  if (wid == 1) {
    float hv = hoverp[0];
    w12 = f2{hv, hv}; w34 = f2{hv, hv};
    wd12 = f2{0.f, 0.f}; wd34 = f2{0.f, 0.f};
    stage(0, 0); stage(1, 1); stage(2, 2);
    asm volatile("s_waitcnt vmcnt(40)" ::: "memory");   // chunk 0 resident
    __builtin_amdgcn_sched_barrier(0);
    motor4(0);
    asm volatile("s_waitcnt lgkmcnt(0)" ::: "memory");  // outs[0] landed
    __builtin_amdgcn_sched_barrier(0);
  } else {
    qA = f2{1.f, 0.f}; qB = f2{0.f, 0.f};
    pq = f2{0.f, 0.f}; rz = f2{0.f, 0.f}; xz = 0.f;
    float l0 = labels[b];
    acc = (double)l0 * (double)l0;   // t=0 term: pred_z[0]=0
  }
  BAR();

  // ---- main loop. Producer at iter j: stage j+3, certify j+1 (issued two
  //      iters ago), motor j+1, lgkm-drain its ds_writes, barrier. Consumer
  //      computes chunk j after the barrier, overlapping producer's iter j+1.
  //      pprm ring: in-flight writers at distances 2,3,4 from B's read;
  //      outs ring: writer (j+2)%3 vs reader j%3 -> distance 2. ----
  for (int j = 0; j < NFULL; ++j) {
    if (wid == 1) {
      int chS = j + 3; if (chS > NFULL) chS = NFULL;    // clamp: dup re-stage
      stage(chS, chS % 5);
      asm volatile("s_waitcnt vmcnt(40)" ::: "memory"); // chunk j+1 resident
      __builtin_amdgcn_sched_barrier(0);
      motor4(j + 1);
      asm volatile("s_waitcnt lgkmcnt(0)" ::: "memory");
      __builtin_amdgcn_sched_barrier(0);
    }
    BAR();
    if (wid == 0) {
      const int pb = j % 5, ob = j % 3;
      float facc = 0.f;
      SetB sa, sb;
      loadB(sa, pb, ob, 0);
      #pragma unroll
      for (int s = 0; s < CHUNK; ++s) {
        SetB& cur = (s & 1) ? sb : sa;
        SetB& nxt = (s & 1) ? sa : sb;
        if (s + 1 < CHUNK) loadB(nxt, pb, ob, s + 1);
        stepB(cur, facc);
      }
      acc += (double)facc;
    }
  }
  // ---- tail: chunk 1023 (3 steps). motor(1023) ran at iter 1022;
  //      producer drains dup stages before the final barrier. ----
  if (wid == 1) {
    asm volatile("s_waitcnt vmcnt(0)" ::: "memory");
    __builtin_amdgcn_sched_barrier(0);
  }
  BAR();
  if (wid == 0) {
    const int pb = NFULL % 5, ob = NFULL % 3;   // 3, 0
    float facc = 0.f;
    SetB sa, sb;
    loadB(sa, pb, ob, 0);
    #pragma unroll
    for (int s = 0; s < 3; ++s) {
      SetB& cur = (s & 1) ? sb : sa;
      SetB& nxt = (s & 1) ? sa : sb;
      if (s + 1 < 3) loadB(nxt, pb, ob, s + 1);
      stepB(cur, facc);
    }
    acc += (double)facc;
    if (lane < 32) bsum[b] = acc;     // upper 32 lanes are duplicates
  }
}

// ---- fallback (no workspace): inline scalar params, no staging ----
__global__ __launch_bounds__(64, 1) void k_sim_fb(
    const float* __restrict__ logits,
    const float* __restrict__ u1, const float* __restrict__ u2,
    const float* __restrict__ u3, const float* __restrict__ u4,
    const float* __restrict__ mxM, const float* __restrict__ mnM,
    const float* __restrict__ labels,
    const float* __restrict__ hoverp, double* __restrict__ bsum) {
  int b = blockIdx.x * 64 + threadIdx.x;
  float hv = hoverp[0];
  Carry c;
  c.xz = 0.f; c.q0 = 1.f; c.q1 = 0.f; c.q2 = 0.f; c.q3 = 0.f;
  c.zd = 0.f; c.pv = 0.f; c.qv = 0.f; c.rv = 0.f;
  c.w1 = hv; c.w2 = hv; c.w3 = hv; c.w4 = hv;
  c.wd1 = 0.f; c.wd2 = 0.f; c.wd3 = 0.f; c.wd4 = 0.f;
  float l0 = labels[b];
  double acc = (double)l0 * (double)l0;
  for (int t = 1; t < T_STEPS; ++t) {
    Pk p = computePk((size_t)t * B_N + b, logits, u1, u2, u3, u4, mxM, mnM, labels);
    float facc = 0.f;
    stepOne(c, p, facc);
    acc += (double)facc;
  }
  bsum[b] = acc;
}

// fallback kth (only used when workspace too small for fused path)
__global__ void k_kth_fb(const float* __restrict__ logits, float* __restrict__ partial) {
  __shared__ float sm[256];
  float a = 0.f;
  const int n = T_STEPS * B_N;
  for (int i = blockIdx.x * 256 + threadIdx.x; i < n; i += 8192 * 256)
    a += (1.0f + (0.5f - logits[(size_t)i * 12 + 7]) * 0.95f) * 1.076e-05f;
  sm[threadIdx.x] = a; __syncthreads();
  for (int s = 128; s; s >>= 1) {
    if (threadIdx.x < s) sm[threadIdx.x] += sm[threadIdx.x + s];
    __syncthreads();
  }
  if (threadIdx.x == 0) partial[blockIdx.x] = sm[0];
}

// ---- kernel 5: final deterministic reduce ----
__global__ void k_final(const double* __restrict__ bsum, float* __restrict__ out) {
  __shared__ double sm[512];
  sm[threadIdx.x] = bsum[threadIdx.x];
  __syncthreads();
  for (int s = 256; s; s >>= 1) {
    if (threadIdx.x < s) sm[threadIdx.x] += sm[threadIdx.x + s];
    __syncthreads();
  }
  if (threadIdx.x == 0) out[0] = (float)(sm[0] * (1.0 / 2097152.0));
}

extern "C" void kernel_launch(void* const* d_in, const int* in_sizes, int n_in,
                              void* d_out, int out_size, void* d_ws, size_t ws_size,
                              hipStream_t stream) {
  const float* labels = (const float*)d_in[0];
  const float* logits = (const float*)d_in[1];
  const float* u1 = (const float*)d_in[2];
  const float* u2 = (const float*)d_in[3];
  const float* u3 = (const float*)d_in[4];
  const float* u4 = (const float*)d_in[5];
  const float* mxM = (const float*)d_in[6];
  const float* mnM = (const float*)d_in[7];
  float* out = (float*)d_out;

  char* ws = (char*)d_ws;
  float*  hover   = (float*)(ws);            // 256 B
  float*  partial = (float*)(ws + 1024);     // 8192 floats = 32 KB
  double* bsum    = (double*)(ws + 34816);   // 4 KB
  float4* pack    = (float4*)(ws + 40960);
  size_t need = 40960 + (size_t)T_STEPS * B_N * 80;
  bool pre = (ws_size >= need);

  if (pre) {
    k_pre  <<<8192, 256, 0, stream>>>(logits, u1, u2, u3, u4, mxM, mnM, labels,
                                      pack, partial);
    k_hover<<<1, 1024, 0, stream>>>(partial, hover);
    k_simsp<<<16, 128, 0, stream>>>(pack, labels, hover, bsum);
  } else {
    // minimal-workspace path
    float* partial2 = (float*)(ws + 1024);
    k_kth_fb<<<8192, 256, 0, stream>>>(logits, partial2);
    k_hover <<<1, 1024, 0, stream>>>(partial2, hover);
    k_sim_fb<<<8, 64, 0, stream>>>(logits, u1, u2, u3, u4, mxM, mnM, labels,
                                   hover, bsum);
  }
  k_final<<<1, 512, 0, stream>>>(bsum, out);
}

// Round 17
// 665.949 us; speedup vs baseline: 1.6176x; 1.6176x over previous
//
#include <hip/hip_runtime.h>
#include <math.h>

#define T_STEPS 4096
#define B_N     512
#define CHUNK   4
#define NFULL   1023   // full chunks 0..1022 (4 steps each): t = 1..4092
// tail chunk 1023: 3 steps, t = 4093..4095; lives in buf 1023%5 == 3

typedef float f2 __attribute__((ext_vector_type(2)));

// ---- packed-f32 VOP3P helpers (verified r10-r15, absmax 0.0) ----
__device__ __forceinline__ f2 pk_fma(f2 a, f2 b, f2 c){ f2 d; asm("v_pk_fma_f32 %0, %1, %2, %3" : "=v"(d) : "v"(a), "v"(b), "v"(c)); return d; }
__device__ __forceinline__ f2 pk_mul(f2 a, f2 b){ f2 d; asm("v_pk_mul_f32 %0, %1, %2" : "=v"(d) : "v"(a), "v"(b)); return d; }
__device__ __forceinline__ f2 pk_add(f2 a, f2 b){ f2 d; asm("v_pk_add_f32 %0, %1, %2" : "=v"(d) : "v"(a), "v"(b)); return d; }
__device__ __forceinline__ f2 pk_sub(f2 a, f2 b){ f2 d; asm("v_pk_add_f32 %0, %1, %2 neg_lo:[0,1] neg_hi:[0,1]" : "=v"(d) : "v"(a), "v"(b)); return d; }
__device__ __forceinline__ f2 pk_dd(f2 dP){ f2 d; asm("v_pk_add_f32 %0, %1, %1 op_sel:[0,1] op_sel_hi:[0,1] neg_lo:[0,1] neg_hi:[0,0]" : "=v"(d) : "v"(dP)); return d; }
// aP=(x,y) -> (y-x, x+y)  : (dqd, ssum) in one op
__device__ __forceinline__ f2 pk_dq(f2 aP){ f2 d; asm("v_pk_add_f32 %0, %1, %1 op_sel:[0,1] op_sel_hi:[0,1] neg_lo:[1,0] neg_hi:[0,0]" : "=v"(d) : "v"(aP)); return d; }
__device__ __forceinline__ f2 pk_vq(f2 a, f2 b){ f2 d; asm("v_pk_add_f32 %0, %1, %2 op_sel:[0,1] op_sel_hi:[1,0]" : "=v"(d) : "v"(a), "v"(b)); return d; }
__device__ __forceinline__ f2 pk_t01a(f2 pq, f2 qA){ f2 d; asm("v_pk_mul_f32 %0, %1, %2 op_sel:[0,1] op_sel_hi:[0,0]" : "=v"(d) : "v"(pq), "v"(qA)); return d; }
__device__ __forceinline__ f2 pk_t01b(f2 pq, f2 qB, f2 acc){ asm("v_pk_fma_f32 %0, %1, %2, %0 op_sel:[1,0,0] op_sel_hi:[1,1,1] neg_hi:[0,1,0]" : "+v"(acc) : "v"(pq), "v"(qB)); return acc; }
__device__ __forceinline__ f2 pk_t01c(f2 rz, f2 qB, f2 acc){ asm("v_pk_fma_f32 %0, %1, %2, %0 op_sel:[0,1,0] op_sel_hi:[0,0,1]" : "+v"(acc) : "v"(rz), "v"(qB)); return acc; }
__device__ __forceinline__ f2 pk_t23a(f2 pq, f2 qA){ f2 d; asm("v_pk_mul_f32 %0, %1, %2 op_sel:[1,0] op_sel_hi:[1,1]" : "=v"(d) : "v"(pq), "v"(qA)); return d; }
__device__ __forceinline__ f2 pk_t23b(f2 pq, f2 qB, f2 acc){ asm("v_pk_fma_f32 %0, %1, %2, %0 op_sel:[0,1,0] op_sel_hi:[0,0,1] neg_hi:[0,1,0]" : "+v"(acc) : "v"(pq), "v"(qB)); return acc; }
__device__ __forceinline__ f2 pk_t23c(f2 rz, f2 qA, f2 acc){ asm("v_pk_fma_f32 %0, %1, %2, %0 op_sel:[0,1,0] op_sel_hi:[0,0,1] neg_lo:[0,1,0]" : "+v"(acc) : "v"(rz), "v"(qA)); return acc; }
__device__ __forceinline__ f2 pk_s1p(f2 pq, f2 rz){ f2 d; asm("v_pk_mul_f32 %0, %1, %2 op_sel:[1,0] op_sel_hi:[0,0]" : "=v"(d) : "v"(pq), "v"(rz)); return d; }
__device__ __forceinline__ f2 pk_s2p(f2 pq, f2 ws){ f2 d; asm("v_pk_mul_f32 %0, %1, %2 op_sel:[1,0] op_sel_hi:[0,1]" : "=v"(d) : "v"(pq), "v"(ws)); return d; }
__device__ __forceinline__ float med3f(float x, float a, float b){ float d; asm("v_med3_f32 %0, %1, %2, %3" : "=v"(d) : "v"(x), "v"(a), "v"(b)); return d; }

// bare workgroup barrier: NO implicit vmcnt(0) drain (unlike __syncthreads).
// Producer certifies residency with its own counted vmcnt BEFORE this.
#define BAR() __builtin_amdgcn_s_barrier()

// packed param layout, 5 float4 = 80B per (t,b):
// F0={KU1,KU2,KU3,KU4} F1={A,A,mn,mx} F2={cA,cC,-cB,cD}
// F3={cdym,cdxm,cE,cq} F4={cthr,-cdx,label,0}
union PkU { float4 v[5]; };

struct CarryP {
  f2 w12, w34, wd12, wd34, qA, qB, pq, rz;  // rz = (rv, zd)
  float xz;
};

__device__ __forceinline__ void stepP(CarryP& c, const float4* F, float& facc,
                                      f2 TT, f2 HT, f2 HP) {
  const float TAU = 0.005f, TAUG = 0.04905f;
  f2 KU12 = {F[0].x, F[0].y}, KU34 = {F[0].z, F[0].w};
  f2 AA   = {F[1].x, F[1].y};
  float mn = F[1].z, mx = F[1].w;
  f2 cAC = {F[2].x, F[2].y}, cBD = {F[2].z, F[2].w};
  f2 cdymxm = {F[3].x, F[3].y};
  float cE = F[3].z, cq = F[3].w;
  float cthr = F[4].x, mcdx = F[4].y, label = F[4].z;

  f2 wdd12 = pk_sub(pk_fma(AA, c.wd12, KU12), c.w12);
  f2 wdd34 = pk_sub(pk_fma(AA, c.wd34, KU34), c.w34);
  f2 wc12, wc34;                        // clamp via med3 (mn<mx always)
  wc12.x = med3f(c.w12.x, mn, mx); wc12.y = med3f(c.w12.y, mn, mx);
  wc34.x = med3f(c.w34.x, mn, mx); wc34.y = med3f(c.w34.y, mn, mx);
  f2 s12 = pk_mul(wc12, wc12), s34 = pk_mul(wc34, wc34);
  f2 aP = pk_add(s12, s34);
  f2 dP = pk_sub(s12, s34);
  f2 dq = pk_dq(aP);                    // (dqd, ssum)
  float dqd = dq.x, ssum = dq.y;
  f2 dd = pk_dd(dP);
  f2 tw = pk_add(wc12, wc34);
  float wsum = tw.x - tw.y;
  f2 qs1 = pk_mul(c.qA, c.qA), qs2 = pk_mul(c.qB, c.qB);
  f2 vq = pk_vq(qs1, qs2);
  float qq = vq.x - vq.y;
  float zd = c.rz.y;
  float zdm = zd * fabsf(zd);
  float nzd = fmaf(mcdx, zdm, zd);
  float Thr2 = cthr * ssum;
  nzd = fmaf(Thr2, qq, nzd) - TAUG;
  f2 t01 = pk_t01a(c.pq, c.qA);
  t01 = pk_t01b(c.pq, c.qB, t01);
  t01 = pk_t01c(c.rz, c.qB, t01);
  f2 t23 = pk_t23a(c.pq, c.qA);
  t23 = pk_t23b(c.pq, c.qB, t23);
  t23 = pk_t23c(c.rz, c.qA, t23);
  f2 nqA = pk_fma(HT, t01, c.qA);
  f2 nqB = pk_fma(HP, t23, c.qB);
  f2 sp1 = pk_s1p(c.pq, c.rz);
  f2 ws2 = {wsum, wsum};
  f2 sp2 = pk_s2p(c.pq, ws2);
  f2 npq = pk_fma(cAC, sp1, c.pq);
  npq = pk_fma(cBD, sp2, npq);
  npq = pk_fma(cdymxm, dd, npq);
  float nrv = fmaf(cE, c.pq.x * c.pq.y, c.rz.x);
  nrv = fmaf(cq, dqd, nrv);
  float nxz = fmaf(TAU, nzd, c.xz);
  float dlt = nxz - c.xz;
  float xznew = (fabsf(dlt) <= 400.0f) ? nxz : c.xz;   // false for NaN/Inf
  float e = xznew - label;
  facc = fmaf(e, e, facc);
  f2 nw12 = pk_fma(TT, c.wd12, wc12);
  f2 nw34 = pk_fma(TT, c.wd34, wc34);
  c.wd12 = pk_fma(TT, wdd12, c.wd12);
  c.wd34 = pk_fma(TT, wdd34, c.wd34);
  c.w12 = nw12; c.w34 = nw34;
  c.qA = nqA; c.qB = nqB; c.pq = npq;
  c.rz = f2{nrv, nzd}; c.xz = xznew;
}

// ================= scalar path (fallback only) =================
struct Pk {
  float KU1, KU2, KU3, KU4, A, mn, mx, cthr;
  float cdym, cdxm, cq, cdx, cA, cB, cC, cD, cE, label, pad0, pad1;
};
__device__ __forceinline__ float sc_ref(float g, float base) {
  return (1.0f + (0.5f - g) * 0.95f) * base;
}
struct Carry {
  float xz, q0, q1, q2, q3, zd, pv, qv, rv;
  float w1, w2, w3, w4, wd1, wd2, wd3, wd4;
};
__device__ __forceinline__ Pk computePk(size_t i,
    const float* __restrict__ logits,
    const float* __restrict__ u1, const float* __restrict__ u2,
    const float* __restrict__ u3, const float* __restrict__ u4,
    const float* __restrict__ mxM, const float* __restrict__ mnM,
    const float* __restrict__ labels) {
  const float4* lg = (const float4*)logits + i * 3;
  float4 l0 = lg[0], l1 = lg[1], l2 = lg[2];
  float dxm  = sc_ref(l0.x, 0.16f);
  float dym  = sc_ref(l0.y, 0.16f);
  float IBxx = sc_ref(l0.w, 0.0123f);
  float IByy = sc_ref(l1.x, 0.0123f);
  float IBzz = sc_ref(l1.y, 0.0123f);
  float Cd   = sc_ref(l1.z, 0.1f);
  float kTh  = sc_ref(l1.w, 1.076e-05f);
  float kTo  = sc_ref(l2.x, 1.632e-07f);
  float tau2 = sc_ref(l2.y, 0.015f);
  float kp   = sc_ref(l2.z, 1.0f);
  float damp = sc_ref(l2.w, 1.0f);
  const float tau = 0.005f, tauOverMb = tau / 1.2f;
  Pk p;
  float K = kp / (tau2 * tau2);
  p.KU1 = K * u1[i];  p.KU2 = K * u2[i];  p.KU3 = K * u3[i];  p.KU4 = K * u4[i];
  p.A = -2.0f * damp * tau2;
  p.mn = mnM[i];  p.mx = mxM[i];
  p.cthr = kTh * tauOverMb;
  float tx = tau / IBxx, ty = tau / IByy, tz = tau / IBzz;
  p.cdym = kTh * dym * tx;  p.cdxm = kTh * dxm * ty;
  p.cq = kTo * tz;  p.cdx = Cd * tauOverMb;
  p.cA = (IByy - IBzz) * tx;  p.cB = 1e-04f * tx;
  p.cC = (IBzz - IBxx) * ty;  p.cD = 1e-04f * ty;
  p.cE = (IBxx - IByy) * tz;
  p.label = labels[i];  p.pad0 = 0.f; p.pad1 = 0.f;
  return p;
}
__device__ __forceinline__ void stepOne(Carry& c, const Pk& p, float& facc) {
  const float TAU = 0.005f, HTAU = 0.0025f, TAUG = 0.04905f;
  float wdd1 = fmaf(p.A, c.wd1, p.KU1) - c.w1;
  float wdd2 = fmaf(p.A, c.wd2, p.KU2) - c.w2;
  float wdd3 = fmaf(p.A, c.wd3, p.KU3) - c.w3;
  float wdd4 = fmaf(p.A, c.wd4, p.KU4) - c.w4;
  float w1c = fminf(fmaxf(c.w1, p.mn), p.mx);
  float w2c = fminf(fmaxf(c.w2, p.mn), p.mx);
  float w3c = fminf(fmaxf(c.w3, p.mn), p.mx);
  float w4c = fminf(fmaxf(c.w4, p.mn), p.mx);
  float s1 = w1c*w1c, s2 = w2c*w2c, s3 = w3c*w3c, s4 = w4c*w4c;
  float sA = s1+s3, sB = s2+s4, ssum = sA+sB;
  float dymd = (s1+s4)-(s2+s3), dxmd = (s1+s2)-(s3+s4), dqd = sB-sA;
  float Thr2 = p.cthr * ssum;
  float qq = fmaf(c.q0,c.q0,c.q3*c.q3) - fmaf(c.q1,c.q1,c.q2*c.q2);
  float zdm = c.zd * fabsf(c.zd);
  float nzd = fmaf(-p.cdx, zdm, c.zd);
  nzd = fmaf(Thr2, qq, nzd) - TAUG;
  float t0 = fmaf(c.pv,c.q1, fmaf(c.qv,c.q2,  c.rv*c.q3));
  float t1 = fmaf(c.pv,c.q0, fmaf(-c.qv,c.q3, c.rv*c.q2));
  float t2 = fmaf(c.pv,c.q3, fmaf(c.qv,c.q0, -(c.rv*c.q1)));
  float t3 = fmaf(-c.pv,c.q2, fmaf(c.qv,c.q1, c.rv*c.q0));
  float nq0 = fmaf(-HTAU,t0,c.q0), nq1 = fmaf(HTAU,t1,c.q1);
  float nq2 = fmaf(HTAU,t2,c.q2),  nq3 = fmaf(HTAU,t3,c.q3);
  float wsum = (w1c-w2c)+(w3c-w4c);
  float npv = fmaf(p.cA, c.qv*c.rv, c.pv);
  npv = fmaf(-p.cB, wsum*c.qv, npv); npv = fmaf(p.cdym, dymd, npv);
  float nqv = fmaf(p.cC, c.pv*c.rv, c.qv);
  nqv = fmaf(p.cD, wsum*c.pv, nqv);  nqv = fmaf(p.cdxm, dxmd, nqv);
  float nrv = fmaf(p.cE, c.pv*c.qv, c.rv);
  nrv = fmaf(p.cq, dqd, nrv);
  float nxz = fmaf(TAU, nzd, c.xz);
  float d = nxz - c.xz;
  float xznew = (fabsf(d) <= 400.0f) ? nxz : c.xz;
  float e = xznew - p.label;
  facc = fmaf(e, e, facc);
  c.w1 = fmaf(TAU,c.wd1,w1c); c.w2 = fmaf(TAU,c.wd2,w2c);
  c.w3 = fmaf(TAU,c.wd3,w3c); c.w4 = fmaf(TAU,c.wd4,w4c);
  c.wd1 = fmaf(TAU,wdd1,c.wd1); c.wd2 = fmaf(TAU,wdd2,c.wd2);
  c.wd3 = fmaf(TAU,wdd3,c.wd3); c.wd4 = fmaf(TAU,wdd4,c.wd4);
  c.q0=nq0; c.q1=nq1; c.q2=nq2; c.q3=nq3;
  c.pv=npv; c.qv=nqv; c.rv=nrv; c.zd=nzd; c.xz=xznew;
}

__device__ __forceinline__ void gload_lds16(const void* g, void* l) {
  __builtin_amdgcn_global_load_lds(
      (const __attribute__((address_space(1))) void*)g,
      (__attribute__((address_space(3))) void*)l, 16, 0, 0);
}

// ---- kernel 2: finalize hover (8192 partials) ----
__global__ void k_hover(const float* __restrict__ partial, float* __restrict__ hover) {
  __shared__ float sm[1024];
  float a = 0.f;
  #pragma unroll
  for (int k = 0; k < 8; ++k) a += partial[threadIdx.x + k * 1024];
  sm[threadIdx.x] = a;
  __syncthreads();
  for (int s = 512; s; s >>= 1) {
    if (threadIdx.x < s) sm[threadIdx.x] += sm[threadIdx.x + s];
    __syncthreads();
  }
  if (threadIdx.x == 0) {
    float mean = sm[0] * (1.0f / 2097152.0f);
    float h = 1.2f * 9.81f / (4.0f * mean + 1e-12f);
    hover[0] = sqrtf(fmaxf(h, 1e-06f));
  }
}

// ---- kernel 3: param precompute, PACKED layout + fused kTh partial sums ----
__global__ void k_pre(const float* __restrict__ logits,
                      const float* __restrict__ u1, const float* __restrict__ u2,
                      const float* __restrict__ u3, const float* __restrict__ u4,
                      const float* __restrict__ mxM, const float* __restrict__ mnM,
                      const float* __restrict__ labels, float4* __restrict__ pack,
                      float* __restrict__ partial) {
  __shared__ float sm[256];
  size_t i = (size_t)blockIdx.x * 256 + threadIdx.x;  // 8192*256 == T*B exactly
  const float4* lg = (const float4*)logits + i * 3;
  float4 l0 = lg[0], l1 = lg[1], l2 = lg[2];
  float dxm  = sc_ref(l0.x, 0.16f);
  float dym  = sc_ref(l0.y, 0.16f);
  float IBxx = sc_ref(l0.w, 0.0123f);
  float IByy = sc_ref(l1.x, 0.0123f);
  float IBzz = sc_ref(l1.y, 0.0123f);
  float Cd   = sc_ref(l1.z, 0.1f);
  float kTh  = sc_ref(l1.w, 1.076e-05f);
  float kTo  = sc_ref(l2.x, 1.632e-07f);
  float tau2 = sc_ref(l2.y, 0.015f);
  float kp   = sc_ref(l2.z, 1.0f);
  float damp = sc_ref(l2.w, 1.0f);
  const float tau = 0.005f, tauOverMb = tau / 1.2f;
  float K = kp / (tau2 * tau2);
  float A = -2.0f * damp * tau2;
  float tx = tau / IBxx, ty = tau / IByy, tz = tau / IBzz;
  float4* dst = pack + i * 5;
  dst[0] = float4{K * u1[i], K * u2[i], K * u3[i], K * u4[i]};
  dst[1] = float4{A, A, mnM[i], mxM[i]};
  dst[2] = float4{(IByy - IBzz) * tx, (IBzz - IBxx) * ty, -1e-04f * tx, 1e-04f * ty};
  dst[3] = float4{kTh * dym * tx, kTh * dxm * ty, (IBxx - IByy) * tz, kTo * tz};
  dst[4] = float4{kTh * tauOverMb, -(Cd * tauOverMb), labels[i], 0.f};
  // fused kTh partial sum (replaces separate k_kth pass)
  sm[threadIdx.x] = kTh;
  __syncthreads();
  for (int s = 128; s; s >>= 1) {
    if (threadIdx.x < s) sm[threadIdx.x] += sm[threadIdx.x + s];
    __syncthreads();
  }
  if (threadIdx.x == 0) partial[blockIdx.x] = sm[0];
}

// ---- kernel 4: r15's verified 566us structure: producer/consumer waves,
//      bare s_barrier, counted vmcnt, 5-buf ring staged 3 ahead. ----
__global__ __launch_bounds__(128, 1) void k_simpc(
    const float4* __restrict__ pack,
    const float* __restrict__ labels,
    const float* __restrict__ hoverp, double* __restrict__ bsum) {
  __shared__ float4 lds[5][CHUNK][5][64];   // 100 KB
  const int lane = threadIdx.x & 63;
  const int wid  = threadIdx.x >> 6;
  const int b = blockIdx.x * 32 + (lane & 31);   // 16 blocks x 32 = 512

  const char* packb = (const char*)pack + (size_t)b * 80;

  auto stage = [&](int chS, int bufS) {
    float4* dstb = &lds[bufS][0][0][0];
    #pragma unroll
    for (int s = 0; s < CHUNK; ++s) {
      int t = 1 + chS * CHUNK + s;
      if (t > T_STEPS - 1) t = T_STEPS - 1;     // clamp (tail pad)
      const char* src = packb + (size_t)t * (B_N * 80);
      #pragma unroll
      for (int k = 0; k < 5; ++k)
        gload_lds16(src + 16 * k, (void*)(dstb + (s * 5 + k) * 64));
    }
  };

  // prologue: producer stages chunks 0,1,2 (60 outstanding <= 63 cap);
  // vmcnt(40) retires chunk 0's 20 loads; chunks 1,2 stay in flight
  // across the bare barrier (writer bufs 1,2 vs reader buf 0: safe).
  if (wid == 1) {
    stage(0, 0); stage(1, 1); stage(2, 2);
    asm volatile("s_waitcnt vmcnt(40)" ::: "memory");
    __builtin_amdgcn_sched_barrier(0);
  }
  BAR();

  CarryP c;
  double acc = 0.0;
  f2 TT = {0.005f, 0.005f}, HT = {-0.0025f, 0.0025f}, HP = {0.0025f, 0.0025f};
  if (wid == 0) {
    float hv = hoverp[0];
    c.w12 = f2{hv, hv}; c.w34 = f2{hv, hv};
    c.wd12 = f2{0.f, 0.f}; c.wd34 = f2{0.f, 0.f};
    c.qA = f2{1.f, 0.f}; c.qB = f2{0.f, 0.f};
    c.pq = f2{0.f, 0.f}; c.rz = f2{0.f, 0.f}; c.xz = 0.f;
    float l0 = labels[b];
    acc = (double)l0 * (double)l0;   // t=0 term: pred_z[0]=0
  }

  PkU pA, pB;
  // main loop: at iter j producer stages j+3 (buf (j+3)%5, clamped) then
  // vmcnt(40) retires chunk j+1 (issued two chunk-times ago). Consumer
  // computes chunk j from buf j%5. In-flight writers {j+2,j+3} and the
  // just-certified j+1 are at ring distances 1,2,3 mod 5 from reader j.
  for (int j = 0; j < NFULL; ++j) {
    if (wid == 1) {
      int chS = j + 3; if (chS > NFULL) chS = NFULL;   // clamp: re-stage 1023
      stage(chS, chS % 5);
      asm volatile("s_waitcnt vmcnt(40)" ::: "memory");
      __builtin_amdgcn_sched_barrier(0);
    }
    BAR();
    if (wid == 0) {
      const float4* Lb = &lds[j % 5][0][0][0];
      float facc = 0.f;
      #pragma unroll
      for (int k = 0; k < 5; ++k) pA.v[k] = Lb[k * 64 + lane];
      #pragma unroll
      for (int s = 0; s < CHUNK; ++s) {
        PkU& cur = (s & 1) ? pB : pA;
        PkU& nxt = (s & 1) ? pA : pB;
        if (s + 1 < CHUNK) {
          #pragma unroll
          for (int k = 0; k < 5; ++k) nxt.v[k] = Lb[((s + 1) * 5 + k) * 64 + lane];
        }
        stepP(c, cur.v, facc, TT, HT, HP);
      }
      acc += (double)facc;
    }
  }
  // tail: chunk 1023 (buf 3), steps t = 4093..4095. Producer drains all
  // (including clamped duplicate stages) before the final barrier.
  if (wid == 1) {
    asm volatile("s_waitcnt vmcnt(0)" ::: "memory");
    __builtin_amdgcn_sched_barrier(0);
  }
  BAR();
  if (wid == 0) {
    const float4* Lb = &lds[NFULL % 5][0][0][0];   // buf 3
    float facc = 0.f;
    #pragma unroll
    for (int k = 0; k < 5; ++k) pA.v[k] = Lb[k * 64 + lane];
    #pragma unroll
    for (int s = 0; s < 3; ++s) {
      PkU& cur = (s & 1) ? pB : pA;
      PkU& nxt = (s & 1) ? pA : pB;
      if (s + 1 < 3) {
        #pragma unroll
        for (int k = 0; k < 5; ++k) nxt.v[k] = Lb[((s + 1) * 5 + k) * 64 + lane];
      }
      stepP(c, cur.v, facc, TT, HT, HP);
    }
    acc += (double)facc;
    if (lane < 32) bsum[b] = acc;     // upper 32 lanes are duplicates
  }
}

// ---- fallback (no workspace): inline scalar params, no staging ----
__global__ __launch_bounds__(64, 1) void k_sim_fb(
    const float* __restrict__ logits,
    const float* __restrict__ u1, const float* __restrict__ u2,
    const float* __restrict__ u3, const float* __restrict__ u4,
    const float* __restrict__ mxM, const float* __restrict__ mnM,
    const float* __restrict__ labels,
    const float* __restrict__ hoverp, double* __restrict__ bsum) {
  int b = blockIdx.x * 64 + threadIdx.x;
  float hv = hoverp[0];
  Carry c;
  c.xz = 0.f; c.q0 = 1.f; c.q1 = 0.f; c.q2 = 0.f; c.q3 = 0.f;
  c.zd = 0.f; c.pv = 0.f; c.qv = 0.f; c.rv = 0.f;
  c.w1 = hv; c.w2 = hv; c.w3 = hv; c.w4 = hv;
  c.wd1 = 0.f; c.wd2 = 0.f; c.wd3 = 0.f; c.wd4 = 0.f;
  float l0 = labels[b];
  double acc = (double)l0 * (double)l0;
  for (int t = 1; t < T_STEPS; ++t) {
    Pk p = computePk((size_t)t * B_N + b, logits, u1, u2, u3, u4, mxM, mnM, labels);
    float facc = 0.f;
    stepOne(c, p, facc);
    acc += (double)facc;
  }
  bsum[b] = acc;
}

// fallback kth (only used when workspace too small for fused path)
__global__ void k_kth_fb(const float* __restrict__ logits, float* __restrict__ partial) {
  __shared__ float sm[256];
  float a = 0.f;
  const int n = T_STEPS * B_N;
  for (int i = blockIdx.x * 256 + threadIdx.x; i < n; i += 8192 * 256)
    a += (1.0f + (0.5f - logits[(size_t)i * 12 + 7]) * 0.95f) * 1.076e-05f;
  sm[threadIdx.x] = a; __syncthreads();
  for (int s = 128; s; s >>= 1) {
    if (threadIdx.x < s) sm[threadIdx.x] += sm[threadIdx.x + s];
    __syncthreads();
  }
  if (threadIdx.x == 0) partial[blockIdx.x] = sm[0];
}

// ---- kernel 5: final deterministic reduce ----
__global__ void k_final(const double* __restrict__ bsum, float* __restrict__ out) {
  __shared__ double sm[512];
  sm[threadIdx.x] = bsum[threadIdx.x];
  __syncthreads();
  for (int s = 256; s; s >>= 1) {
    if (threadIdx.x < s) sm[threadIdx.x] += sm[threadIdx.x + s];
    __syncthreads();
  }
  if (threadIdx.x == 0) out[0] = (float)(sm[0] * (1.0 / 2097152.0));
}

extern "C" void kernel_launch(void* const* d_in, const int* in_sizes, int n_in,
                              void* d_out, int out_size, void* d_ws, size_t ws_size,
                              hipStream_t stream) {
  const float* labels = (const float*)d_in[0];
  const float* logits = (const float*)d_in[1];
  const float* u1 = (const float*)d_in[2];
  const float* u2 = (const float*)d_in[3];
  const float* u3 = (const float*)d_in[4];
  const float* u4 = (const float*)d_in[5];
  const float* mxM = (const float*)d_in[6];
  const float* mnM = (const float*)d_in[7];
  float* out = (float*)d_out;

  char* ws = (char*)d_ws;
  float*  hover   = (float*)(ws);            // 256 B
  float*  partial = (float*)(ws + 1024);     // 8192 floats = 32 KB
  double* bsum    = (double*)(ws + 34816);   // 4 KB
  float4* pack    = (float4*)(ws + 40960);
  size_t need = 40960 + (size_t)T_STEPS * B_N * 80;
  bool pre = (ws_size >= need);

  if (pre) {
    k_pre  <<<8192, 256, 0, stream>>>(logits, u1, u2, u3, u4, mxM, mnM, labels,
                                      pack, partial);
    k_hover<<<1, 1024, 0, stream>>>(partial, hover);
    k_simpc<<<16, 128, 0, stream>>>(pack, labels, hover, bsum);
  } else {
    // minimal-workspace path
    float* partial2 = (float*)(ws + 1024);
    k_kth_fb<<<8192, 256, 0, stream>>>(logits, partial2);
    k_hover <<<1, 1024, 0, stream>>>(partial2, hover);
    k_sim_fb<<<8, 64, 0, stream>>>(logits, u1, u2, u3, u4, mxM, mnM, labels,
                                   hover, bsum);
  }
  k_final<<<1, 512, 0, stream>>>(bsum, out);
}